// Round 1
// baseline (485.947 us; speedup 1.0000x reference)
//
#include <hip/hip_runtime.h>

// SparseConv2D: 32x112x112x128 fp32 NHWC, 3x3 SAME, 126 out ch x 5 taps.
// Implicit GEMM on bf16 MFMA, dense-9-tap. M=112 (one row), N=128, K=9*128.
// R4: (a) wave re-tile 2Mx2N, nf=4 -> each A-frag LDS read feeds 4 MFMAs
//     (block ds_read count halved 1008->504); B per-r-group in regs,
//     double-buffered, issued BEFORE the A HBM prefetch (vmcnt ordering).
//     (b) XCD-chunked block swizzle: 448 consecutive rows (4 images) per XCD
//     so the 3-row halo re-read hits per-XCD L2 (FETCH ~308->~215 MB).

typedef __attribute__((ext_vector_type(8))) __bf16 bf16x8;
typedef __attribute__((ext_vector_type(4))) float f32x4;

__device__ __forceinline__ unsigned short f2bf(float f) {
  unsigned int u = __builtin_bit_cast(unsigned int, f);
  u += 0x7fffu + ((u >> 16) & 1u);   // RNE (inputs are finite normals)
  return (unsigned short)(u >> 16);
}

// Bws[p][cc][n][c] bf16: dense kernel, n in [0,128) (126..127 zero), c in [0,32)
__global__ __launch_bounds__(256) void build_B(const float* __restrict__ sk,
                                               const int* __restrict__ patterns,
                                               unsigned short* __restrict__ Bws) {
  int idx = blockIdx.x * 256 + threadIdx.x;
  if (idx >= 9 * 128 * 128) return;
  int c = idx & 127;
  int n = (idx >> 7) & 127;
  int p = idx >> 14;
  float v = 0.f;
  if (n < 126) {
#pragma unroll
    for (int j = 0; j < 5; ++j)
      if (patterns[n * 5 + j] == p) v = sk[(j * 128 + c) * 126 + n];
  }
  int cc = c >> 5, cl = c & 31;
  Bws[(((p * 4 + cc) * 128) + n) * 32 + cl] = f2bf(v);
}

__global__ __launch_bounds__(256, 2) void conv_main(const float* __restrict__ in,
                                                    const unsigned short* __restrict__ Bws,
                                                    const float* __restrict__ bias,
                                                    float* __restrict__ out) {
  // single A buffer: 3 halo rows x 114 px x 32ch, ch padded 32->40 (80 B rows)
  __shared__ unsigned short Alds[3 * 114 * 40];      // 27,360 B

  const int tid = threadIdx.x;
  // XCD-chunked swizzle: blockIdx round-robins XCDs with period 8; give each
  // XCD 448 consecutive work-ids (= 4 whole images) for halo L2 reuse.
  const int bid = ((blockIdx.x & 7) * 448) + (blockIdx.x >> 3);
  const int nimg = bid / 112;
  const int y = bid - nimg * 112;
  const int lane = tid & 63;
  const int w = tid >> 6;
  const int wm = w >> 1;            // x-group: 0 -> x[0,64) (4 mt), 1 -> x[64,112) (3 mt)
  const int wn = w & 1;             // n-half: out ch [64*wn, 64*wn+64)
  const int quad = lane >> 4;
  const int lrow = lane & 15;
  const int xbase = wm * 64;

  const float* inb = in + (size_t)nimg * 112 * 112 * 128;

  f32x4 acc[4][4];
#pragma unroll
  for (int mt = 0; mt < 4; ++mt)
#pragma unroll
    for (int j = 0; j < 4; ++j) acc[mt][j] = (f32x4)0.f;

  // A prefetch: rows y-1..y+1, hx in [0,114) (gx=hx-1), 32 ch of chunk cc.
  // 3*114*8 = 2736 float4 pieces; thread handles tid + 256*it, it in [0,11).
  float4 pf[11];
  auto loadA = [&](int cc) {
#pragma unroll
    for (int it = 0; it < 11; ++it) {
      int i = tid + it * 256;
      float4 v = make_float4(0.f, 0.f, 0.f, 0.f);
      if (i < 2736) {
        int c4 = i & 7;
        int rest = i >> 3;
        int r = rest / 114;
        int hx = rest - r * 114;
        int gy = y + r - 1;
        int gx = hx - 1;
        if ((unsigned)gy < 112u && (unsigned)gx < 112u)
          v = *(const float4*)(inb + ((size_t)gy * 112 + gx) * 128 + cc * 32 + c4 * 4);
      }
      pf[it] = v;
    }
  };
  auto writeA = [&]() {
#pragma unroll
    for (int it = 0; it < 11; ++it) {
      int i = tid + it * 256;
      if (i < 2736) {
        int c4 = i & 7;
        int rest = i >> 3;
        int r = rest / 114;
        int hx = rest - r * 114;
        ushort4 s;
        s.x = f2bf(pf[it].x); s.y = f2bf(pf[it].y);
        s.z = f2bf(pf[it].z); s.w = f2bf(pf[it].w);
        *(ushort4*)&Alds[(r * 114 + hx) * 40 + c4 * 4] = s;
      }
    }
  };

  // B fragments for one r-group (3 taps x 4 n-frags), straight from L2-hot Bws.
  auto loadB3 = [&](bf16x8 (&bg)[3][4], int cc, int r) {
#pragma unroll
    for (int pp = 0; pp < 3; ++pp)
#pragma unroll
      for (int j = 0; j < 4; ++j)
        bg[pp][j] = *(const bf16x8*)(Bws +
            (((size_t)((r * 3 + pp) * 4 + cc) * 128 + wn * 64 + j * 16 + lrow) * 32 + quad * 8));
  };

  auto mfma_group = [&](int r, bf16x8 (&bg)[3][4]) {
#pragma unroll
    for (int pp = 0; pp < 3; ++pp) {
      const int abase = (r * 114 + pp + lrow + xbase) * 40 + quad * 8;
#pragma unroll
      for (int mt = 0; mt < 3; ++mt) {
        bf16x8 a = *(const bf16x8*)&Alds[abase + mt * (16 * 40)];
#pragma unroll
        for (int j = 0; j < 4; ++j)
          acc[mt][j] = __builtin_amdgcn_mfma_f32_16x16x32_bf16(a, bg[pp][j], acc[mt][j], 0, 0, 0);
      }
      if (!wm) {  // wave-uniform: x-group 0 owns a 4th M-tile (x 48..63)
        bf16x8 a = *(const bf16x8*)&Alds[abase + 3 * (16 * 40)];
#pragma unroll
        for (int j = 0; j < 4; ++j)
          acc[3][j] = __builtin_amdgcn_mfma_f32_16x16x32_bf16(a, bg[pp][j], acc[3][j], 0, 0, 0);
      }
    }
  };

  loadA(0);
  writeA();
  __syncthreads();

#pragma unroll 1
  for (int cc = 0; cc < 4; ++cc) {
    bf16x8 bA[3][4], bB[3][4];
    loadB3(bA, cc, 0);          // issued before loadA: B waits don't drain HBM pf
    loadB3(bB, cc, 1);
    if (cc < 3) loadA(cc + 1);  // HBM loads in flight during the MFMAs below

    mfma_group(0, bA);
    loadB3(bA, cc, 2);          // r=2 group; its wait lands after ~2 groups of
                                // compute, by which time pf is complete anyway
    mfma_group(1, bB);
    mfma_group(2, bA);

    if (cc < 3) {
      __syncthreads();   // everyone done reading Alds[cc]
      writeA();          // waits on prefetch (hidden by the compute above)
      __syncthreads();   // Alds[cc+1] ready
    }
  }

  // epilogue: C/D layout col = lane&15 (N), row = quad*4 + reg (M)
  const int kb = wn * 64 + lrow;
  float bv[4];
#pragma unroll
  for (int j = 0; j < 4; ++j) {
    int k = kb + j * 16;
    bv[j] = bias[k < 126 ? k : 125];
  }
  float* outrow = out + ((size_t)(nimg * 112 + y)) * 112 * 126;
#pragma unroll
  for (int mt = 0; mt < 3; ++mt) {
#pragma unroll
    for (int rg = 0; rg < 4; ++rg) {
      int x = xbase + mt * 16 + quad * 4 + rg;
      float* o = outrow + (size_t)x * 126;
#pragma unroll
      for (int j = 0; j < 4; ++j) {
        int k = kb + j * 16;
        if (k < 126) { float v = acc[mt][j][rg] + bv[j]; o[k] = v > 0.f ? v : 0.f; }
      }
    }
  }
  if (!wm) {
#pragma unroll
    for (int rg = 0; rg < 4; ++rg) {
      int x = xbase + 3 * 16 + quad * 4 + rg;
      float* o = outrow + (size_t)x * 126;
#pragma unroll
      for (int j = 0; j < 4; ++j) {
        int k = kb + j * 16;
        if (k < 126) { float v = acc[3][j][rg] + bv[j]; o[k] = v > 0.f ? v : 0.f; }
      }
    }
  }
}

extern "C" void kernel_launch(void* const* d_in, const int* in_sizes, int n_in,
                              void* d_out, int out_size, void* d_ws, size_t ws_size,
                              hipStream_t stream) {
  const float* in = (const float*)d_in[0];        // (32,112,112,128) fp32
  const float* sk = (const float*)d_in[1];        // (5,128,126) fp32
  const float* bias = (const float*)d_in[2];      // (126,) fp32
  const int* patterns = (const int*)d_in[3];      // (126,5) int32
  float* out = (float*)d_out;                     // (32,112,112,126) fp32
  unsigned short* Bws = (unsigned short*)d_ws;    // 9*4*128*32 bf16 = 294,912 B

  build_B<<<dim3(576), dim3(256), 0, stream>>>(sk, patterns, Bws);
  conv_main<<<dim3(32 * 112), dim3(256), 0, stream>>>(in, Bws, bias, out);
}

// Round 2
// 432.303 us; speedup vs baseline: 1.1241x; 1.1241x over previous
//
#include <hip/hip_runtime.h>

// SparseConv2D: 32x112x112x128 fp32 NHWC, 3x3 SAME, 126 out ch x 5 taps.
// Implicit GEMM on bf16 MFMA, dense-9-tap. M=112 (one row), N=128, K=9*128.
// R5: R3 compute structure (4 waves x 32ch, nf=2, ALL 18 B frags loaded before
// the A HBM prefetch so no vmcnt wait ever drains the prefetch) + the
// validated XCD-chunked block swizzle from R4 (FETCH 308->121 MB measured).
// R4's nf=4 retile is reverted: its r=2 B-group wait was a vmcnt(0) drain of
// the A prefetch each cc (+50us stall), and the 144-VGPR B footprint needed
// to fix it doesn't fit at 2 blocks/CU.

typedef __attribute__((ext_vector_type(8))) __bf16 bf16x8;
typedef __attribute__((ext_vector_type(4))) float f32x4;

__device__ __forceinline__ unsigned short f2bf(float f) {
  unsigned int u = __builtin_bit_cast(unsigned int, f);
  u += 0x7fffu + ((u >> 16) & 1u);   // RNE (inputs are finite normals)
  return (unsigned short)(u >> 16);
}

// Bws[p][cc][n][c] bf16: dense kernel, n in [0,128) (126..127 zero), c in [0,32)
__global__ __launch_bounds__(256) void build_B(const float* __restrict__ sk,
                                               const int* __restrict__ patterns,
                                               unsigned short* __restrict__ Bws) {
  int idx = blockIdx.x * 256 + threadIdx.x;
  if (idx >= 9 * 128 * 128) return;
  int c = idx & 127;
  int n = (idx >> 7) & 127;
  int p = idx >> 14;
  float v = 0.f;
  if (n < 126) {
#pragma unroll
    for (int j = 0; j < 5; ++j)
      if (patterns[n * 5 + j] == p) v = sk[(j * 128 + c) * 126 + n];
  }
  int cc = c >> 5, cl = c & 31;
  Bws[(((p * 4 + cc) * 128) + n) * 32 + cl] = f2bf(v);
}

__global__ __launch_bounds__(256, 2) void conv_main(const float* __restrict__ in,
                                                    const unsigned short* __restrict__ Bws,
                                                    const float* __restrict__ bias,
                                                    float* __restrict__ out) {
  // single A buffer: 3 halo rows x 114 px x 32ch, ch padded 32->40 (80 B rows,
  // frag reads land uniformly on banks)
  __shared__ unsigned short Alds[3 * 114 * 40];      // 27,360 B

  const int tid = threadIdx.x;
  // XCD-chunked swizzle: blockIdx round-robins XCDs with period 8; give each
  // XCD 448 consecutive work-ids (= 4 whole images) for halo L2 reuse.
  // Bijective: grid 3584 = 8 * 448 exactly.
  const int bid = ((blockIdx.x & 7) * 448) + (blockIdx.x >> 3);
  const int nimg = bid / 112;
  const int y = bid - nimg * 112;
  const int lane = tid & 63;
  const int w = tid >> 6;           // wave id: output cols [32w, 32w+32)
  const int quad = lane >> 4;
  const int lrow = lane & 15;

  const float* inb = in + (size_t)nimg * 112 * 112 * 128;

  f32x4 acc[7][2];
#pragma unroll
  for (int mt = 0; mt < 7; ++mt) { acc[mt][0] = (f32x4)0.f; acc[mt][1] = (f32x4)0.f; }

  // A prefetch: rows y-1..y+1, hx in [0,114) (gx=hx-1), 32 ch of chunk cc.
  // 3*114*8 = 2736 float4 pieces; thread handles tid + 256*it, it in [0,11).
  float4 pf[11];
  auto loadA = [&](int cc) {
#pragma unroll
    for (int it = 0; it < 11; ++it) {
      int i = tid + it * 256;
      float4 v = make_float4(0.f, 0.f, 0.f, 0.f);
      if (i < 2736) {
        int c4 = i & 7;
        int rest = i >> 3;
        int r = rest / 114;
        int hx = rest - r * 114;
        int gy = y + r - 1;
        int gx = hx - 1;
        if ((unsigned)gy < 112u && (unsigned)gx < 112u)
          v = *(const float4*)(inb + ((size_t)gy * 112 + gx) * 128 + cc * 32 + c4 * 4);
      }
      pf[it] = v;
    }
  };
  auto writeA = [&]() {
#pragma unroll
    for (int it = 0; it < 11; ++it) {
      int i = tid + it * 256;
      if (i < 2736) {
        int c4 = i & 7;
        int rest = i >> 3;
        int r = rest / 114;
        int hx = rest - r * 114;
        ushort4 s;
        s.x = f2bf(pf[it].x); s.y = f2bf(pf[it].y);
        s.z = f2bf(pf[it].z); s.w = f2bf(pf[it].w);
        *(ushort4*)&Alds[(r * 114 + hx) * 40 + c4 * 4] = s;
      }
    }
  };

  loadA(0);
  writeA();
  __syncthreads();

#pragma unroll 1
  for (int cc = 0; cc < 4; ++cc) {
    // B frags for this chunk: 9 taps x 2 n-frags, straight from global (L2-hot).
    // Issued BEFORE the A prefetch: waiting on b[p] never drains the HBM loads.
    bf16x8 b[9][2];
#pragma unroll
    for (int p = 0; p < 9; ++p)
#pragma unroll
      for (int j = 0; j < 2; ++j)
        b[p][j] = *(const bf16x8*)(Bws +
            (((size_t)(p * 4 + cc) * 128 + w * 32 + j * 16 + lrow) * 32 + quad * 8));

    if (cc < 3) loadA(cc + 1);   // HBM loads in flight during the 126 MFMAs below

#pragma unroll
    for (int p = 0; p < 9; ++p) {
      const int r = p / 3;          // dy = r-1
      const int px = p - r * 3;     // dx = px-1
      const int abase = (r * 114 + px + lrow) * 40 + quad * 8;
#pragma unroll
      for (int mt = 0; mt < 7; ++mt) {
        bf16x8 a = *(const bf16x8*)&Alds[abase + mt * 16 * 40];
        acc[mt][0] = __builtin_amdgcn_mfma_f32_16x16x32_bf16(a, b[p][0], acc[mt][0], 0, 0, 0);
        acc[mt][1] = __builtin_amdgcn_mfma_f32_16x16x32_bf16(a, b[p][1], acc[mt][1], 0, 0, 0);
      }
    }

    if (cc < 3) {
      __syncthreads();   // everyone done reading Alds[cc]
      writeA();          // waits on prefetch (hidden by the compute above)
      __syncthreads();   // Alds[cc+1] ready
    }
  }

  // epilogue: C/D layout col = lane&15 (N), row = quad*4 + reg (M)
  const int k0 = w * 32 + lrow;
  const int k1 = k0 + 16;
  const float bv0 = bias[k0 < 126 ? k0 : 125];
  const float bv1 = bias[k1 < 126 ? k1 : 125];
  float* outrow = out + ((size_t)(nimg * 112 + y)) * 112 * 126;
#pragma unroll
  for (int mt = 0; mt < 7; ++mt) {
#pragma unroll
    for (int rg = 0; rg < 4; ++rg) {
      int x = mt * 16 + quad * 4 + rg;
      float* o = outrow + (size_t)x * 126;
      if (k0 < 126) { float v = acc[mt][0][rg] + bv0; o[k0] = v > 0.f ? v : 0.f; }
      if (k1 < 126) { float v = acc[mt][1][rg] + bv1; o[k1] = v > 0.f ? v : 0.f; }
    }
  }
}

extern "C" void kernel_launch(void* const* d_in, const int* in_sizes, int n_in,
                              void* d_out, int out_size, void* d_ws, size_t ws_size,
                              hipStream_t stream) {
  const float* in = (const float*)d_in[0];        // (32,112,112,128) fp32
  const float* sk = (const float*)d_in[1];        // (5,128,126) fp32
  const float* bias = (const float*)d_in[2];      // (126,) fp32
  const int* patterns = (const int*)d_in[3];      // (126,5) int32
  float* out = (float*)d_out;                     // (32,112,112,126) fp32
  unsigned short* Bws = (unsigned short*)d_ws;    // 9*4*128*32 bf16 = 294,912 B

  build_B<<<dim3(576), dim3(256), 0, stream>>>(sk, patterns, Bws);
  conv_main<<<dim3(32 * 112), dim3(256), 0, stream>>>(in, Bws, bias, out);
}